// Round 14
// baseline (375.519 us; speedup 1.0000x reference)
//
#include <hip/hip_runtime.h>

// Problem constants
constexpr int BB = 8, NN = 4096, FF = 512, DD = 64, OO = 512;

using short8  = __attribute__((ext_vector_type(8))) short;
using ushort8 = __attribute__((ext_vector_type(8))) unsigned short;
using ushort4v= __attribute__((ext_vector_type(4))) unsigned short;
using f32x4   = __attribute__((ext_vector_type(4))) float;

__device__ __forceinline__ unsigned short f2bf(float f) {
  unsigned int u = __builtin_bit_cast(unsigned int, f);
  return (unsigned short)((u + 0x7FFFu + ((u >> 16) & 1u)) >> 16);
}

__device__ __forceinline__ f32x4 mfma16(short8 a, short8 b, f32x4 c) {
  return __builtin_amdgcn_mfma_f32_16x16x32_bf16(a, b, c, 0, 0, 0);
}

// async global->LDS, 16B per lane; lane l lands at base + l*16 (lane-contiguous)
__device__ __forceinline__ void gl_lds16(const void* g, void* s) {
  __builtin_amdgcn_global_load_lds(
      (const __attribute__((address_space(1))) unsigned int*)g,
      (__attribute__((address_space(3))) unsigned int*)s,
      16, 0, 0);
}

// ---------------- kernel 1: cast x (f32) -> bf16 ----------------
__global__ void cast_x(const float* __restrict__ x, unsigned short* __restrict__ xb) {
  size_t base = ((size_t)blockIdx.x * 256 + threadIdx.x) * 8;
  float4 a = *(const float4*)(x + base);
  float4 b = *(const float4*)(x + base + 4);
  ushort8 o;
  o[0]=f2bf(a.x); o[1]=f2bf(a.y); o[2]=f2bf(a.z); o[3]=f2bf(a.w);
  o[4]=f2bf(b.x); o[5]=f2bf(b.y); o[6]=f2bf(b.z); o[7]=f2bf(b.w);
  *(ushort8*)(xb + base) = o;
}

// ---------------- kernel 2: build Wcat^T [640][512] bf16 + bias[640] ----------------
__global__ void build_w(const float* __restrict__ w1, const float* __restrict__ w2,
                        const float* __restrict__ wgt,
                        const float* __restrict__ b1, const float* __restrict__ b2,
                        unsigned short* __restrict__ Wt, float* __restrict__ bias) {
  int idx = blockIdx.x * 256 + threadIdx.x;   // 640*512 threads
  int j = idx >> 9, kk = idx & 511;
  float v = (j < 64) ? w1[kk * 64 + j]
          : (j < 128) ? w2[kk * 64 + (j - 64)]
                      : wgt[(size_t)kk * 512 + (j - 128)];
  Wt[(size_t)j * 512 + kk] = f2bf(v);
  if (kk == 0) bias[j] = (j < 64) ? b1[j] : (j < 128) ? b2[j - 64] : 0.f;
}

// ---------------- kernel 2b: compact active rows, one block per batch, no atomics ----------------
__global__ void compact_rows(const float* __restrict__ mask, int* __restrict__ cnt,
                             int* __restrict__ ridx) {
  __shared__ int wsum[4];
  __shared__ int base;
  const int b = blockIdx.x;              // 8 blocks
  const int t = threadIdx.x, lane = t & 63, w = t >> 6;
  if (t == 0) base = 0;
  __syncthreads();
  for (int it = 0; it < 16; ++it) {
    int r = it * 256 + t;
    bool act = mask[(b << 12) + r] != 0.f;
    unsigned long long bal = __ballot(act);
    int pre = __popcll(bal & ((1ull << lane) - 1ull));
    if (lane == 0) wsum[w] = __popcll(bal);
    __syncthreads();
    int woff = 0;
    for (int i = 0; i < w; ++i) woff += wsum[i];
    int tot = wsum[0] + wsum[1] + wsum[2] + wsum[3];
    if (act) ridx[(b << 12) + base + woff + pre] = r;
    __syncthreads();
    if (t == 0) base += tot;
    __syncthreads();
  }
  if (t == 0) cnt[b] = base;
}

// ---------------- kernel 2c: zero masked output rows ----------------
__global__ void zero_masked(const float* __restrict__ mask, float* __restrict__ out) {
  int gid = blockIdx.x * 256 + threadIdx.x;  // 32768*128
  int r = gid >> 7, c = (gid & 127) * 4;
  if (mask[r] == 0.f) {
    float4 z = {0.f, 0.f, 0.f, 0.f};
    *(float4*)(out + (size_t)r * 512 + c) = z;
  }
}

// ---------------- kernel 3: fused projection GEMM ----------------
__global__ __launch_bounds__(256, 2) void proj_gemm(
    const unsigned short* __restrict__ X, const unsigned short* __restrict__ Wt,
    const float* __restrict__ bias,
    unsigned short* __restrict__ QK, unsigned short* __restrict__ SupT) {
  __shared__ __align__(16) unsigned short Abuf[128 * 64];
  __shared__ __align__(16) unsigned short Bbuf[128 * 64];
  const int t = threadIdx.x, lane = t & 63, w = t >> 6;
  const int nblk = blockIdx.x;           // 0..4
  const int m0 = blockIdx.y * 128, n0 = nblk * 128;
  const int wm = w & 1, wn = w >> 1;

  f32x4 acc[4][4] = {};
  for (int kt = 0; kt < 8; ++kt) {
    for (int i = 0; i < 4; ++i) {
      int c = i * 4 + w;
      int row = c * 8 + (lane >> 3);
      int k0 = (lane & 7) * 8;
      gl_lds16(X + (size_t)(m0 + row) * 512 + kt * 64 + k0, &Abuf[c * 512]);
      gl_lds16(Wt + (size_t)(n0 + row) * 512 + kt * 64 + k0, &Bbuf[c * 512]);
    }
    __syncthreads();
    short8 af[4][2], bfr[4][2];
    for (int mi = 0; mi < 4; ++mi)
      for (int kc = 0; kc < 2; ++kc) {
        int row = wm * 64 + mi * 16 + (lane & 15);
        int d = kc * 32 + (lane >> 4) * 8;
        af[mi][kc] = *(const short8*)&Abuf[row * 64 + d];
      }
    for (int ni = 0; ni < 4; ++ni)
      for (int kc = 0; kc < 2; ++kc) {
        int col = wn * 64 + ni * 16 + (lane & 15);
        int d = kc * 32 + (lane >> 4) * 8;
        bfr[ni][kc] = *(const short8*)&Bbuf[col * 64 + d];
      }
    for (int mi = 0; mi < 4; ++mi)
      for (int ni = 0; ni < 4; ++ni)
        for (int kc = 0; kc < 2; ++kc)
          acc[mi][ni] = mfma16(af[mi][kc], bfr[ni][kc], acc[mi][ni]);
    __syncthreads();
  }
  for (int mi = 0; mi < 4; ++mi)
    for (int ni = 0; ni < 4; ++ni) {
      int col_g = n0 + wn * 64 + ni * 16 + (lane & 15);
      int row0 = m0 + wm * 64 + mi * 16 + ((lane >> 4) * 4);
      float bv = bias[col_g];
      if (nblk == 0) {
        for (int j = 0; j < 4; ++j)
          QK[(size_t)(row0 + j) * 128 + col_g] = f2bf(acc[mi][ni][j] + bv);
      } else {
        int scol = col_g - 128;
        int b = row0 >> 12, rl = row0 & 4095;
        ushort4v pk;
        for (int j = 0; j < 4; ++j) pk[j] = f2bf(acc[mi][ni][j] + bv);
        *(ushort4v*)&SupT[(size_t)(b * 512 + scol) * 4096 + rl] = pk;
      }
    }
}

// ---------------- kernel 4: fused attention, merged S+PV phase, ONE barrier/iter ----
// Block: 64 rows x 512 cols, 8 waves (64x64 wave tiles), BK=32.
// Iteration kt: [stage(kt+1) -> PV(kt-1) -> S(kt) -> drain -> barrier].
// PV(kt-1) and S(kt) are independent, so each wave's PV MFMAs interleave with
// S's exp/cvt VALU chain in the scheduler (VALU hides under MFMA) instead of
// the whole block alternating phases in lockstep. Buffers: K/V triple (stage
// target (kt+1)%3 != read slot (kt-1)%3 != kt%3; previous reader PV(kt-2)
// finished before the last barrier -> race-free by the R11 invariant: every
// wave drains its own vmcnt+lgkm BEFORE the per-iter barrier). P double.
// Unnormalized exp (logits tiny by construction); divide by l in epilogue.
__global__ __launch_bounds__(512, 2) void attn_kernel(
    const unsigned short* __restrict__ QK, const unsigned short* __restrict__ SupT,
    const int* __restrict__ cnt, const int* __restrict__ ridx,
    float* __restrict__ out) {
  __shared__ __align__(16) unsigned short Kb[3][32 * 64];   // 12KB, src-xor-swizzled
  __shared__ __align__(16) unsigned short Vt[3][512 * 32];  // 96KB, [colL][key], swizzled
  __shared__ __align__(16) unsigned short Pb[2][64 * 40];   // 10KB, [qrow][key] stride 40
  __shared__ float lsh[2][64];
  __shared__ int rsh[64];

  // batch in low bits -> one batch per XCD (L2 affinity)
  const int batch = blockIdx.x & 7;
  const int chunk = blockIdx.x >> 3;       // 0..63
  const int n_act = cnt[batch];
  if (chunk * 64 >= n_act) return;
  const int rem = min(64, n_act - chunk * 64);

  const int t = threadIdx.x, lane = t & 63, w = t >> 6;
  const int keybase = batch << 12;
  const int l15 = lane & 15, lh = lane >> 4;   // lh 0..3
  const int rg = w >> 1, ks = w & 1;           // S role: 16-row group x 16-key strip
  const int wo = w;                            // PV role: 64-col group (0..7)

  if (t < 64) rsh[t] = ridx[(batch << 12) + chunk * 64 + min(t, rem - 1)];
  __syncthreads();

  // Q B-frags (A=K,B=Q S): col=qrow=rg*16+l15, k(d) = kc*32 + lh*8 + j
  short8 aq[2];
  {
    int rl = rsh[rg * 16 + l15];
    const unsigned short* qp = QK + (size_t)(keybase + rl) * 128 + lh * 8;
    aq[0] = *(const short8*)(qp);
    aq[1] = *(const short8*)(qp + 32);
  }

  f32x4 acc[4][4] = {};
  float lacc = 0.f;

  auto stage = [&](int p, int key0) {
    if (w < 4) {  // K tile: 32 keys x 64 d (1 instr, waves 0-3)
      int key = w * 8 + (lane >> 3);
      int q = lane & 7;
      int d0 = (q ^ (key & 7)) * 8;
      gl_lds16(QK + (size_t)(keybase + key0 + key) * 128 + 64 + d0, &Kb[p][w * 512]);
    }
#pragma unroll
    for (int i = 0; i < 4; ++i) {  // Vt tile: 512 cols x 32 keys (4 instr/wave)
      int c = i * 8 + w;                     // 0..31 col-block (16 cols each)
      int colL = c * 16 + (lane >> 2);       // col 0..511
      int k0 = ((lane & 3) ^ ((colL >> 1) & 3)) * 8;
      gl_lds16(SupT + (size_t)(batch * 512 + colL) * 4096 + key0 + k0,
               &Vt[p][c * 512]);
    }
  };

  auto Sphase = [&](int kslot, int pslot) {
    f32x4 st = {};
    int key = ks * 16 + l15;
#pragma unroll
    for (int kc = 0; kc < 2; ++kc) {
      int blk = (kc * 4 + lh) ^ (key & 7);
      short8 kf = *(const short8*)&Kb[kslot][key * 64 + blk * 8];
      st = mfma16(kf, aq[kc], st);
    }
    float e0 = __expf(st[0] * 0.125f), e1 = __expf(st[1] * 0.125f);
    float e2 = __expf(st[2] * 0.125f), e3 = __expf(st[3] * 0.125f);
    lacc += (e0 + e1) + (e2 + e3);
    unsigned u0, u1;
    asm("v_cvt_pk_bf16_f32 %0, %1, %2" : "=v"(u0) : "v"(e0), "v"(e1));
    asm("v_cvt_pk_bf16_f32 %0, %1, %2" : "=v"(u1) : "v"(e2), "v"(e3));
    uint2 pk; pk.x = u0; pk.y = u1;
    *(uint2*)&Pb[pslot][(rg * 16 + l15) * 40 + ks * 16 + lh * 4] = pk;
  };

  auto PVphase = [&](int vslot, int pslot) {
    short8 pa[4];
#pragma unroll
    for (int rf = 0; rf < 4; ++rf)
      pa[rf] = *(const short8*)&Pb[pslot][(rf * 16 + l15) * 40 + lh * 8];
#pragma unroll
    for (int cf = 0; cf < 4; ++cf) {
      int colL = wo * 64 + cf * 16 + l15;
      int blk = lh ^ ((colL >> 1) & 3);
      short8 vb = *(const short8*)&Vt[vslot][colL * 32 + blk * 8];
#pragma unroll
      for (int rf = 0; rf < 4; ++rf)
        acc[rf][cf] = mfma16(pa[rf], vb, acc[rf][cf]);
    }
  };

  // prologue: stage tile 0, drain, barrier
  stage(0, 0);
  asm volatile("s_waitcnt vmcnt(0)" ::: "memory");
  __builtin_amdgcn_s_barrier();

  for (int kt = 0; kt < 128; ++kt) {
    if (kt < 127) stage((kt + 1) % 3, (kt + 1) * 32);  // target's readers done pre-last-barrier
    if (kt > 0) PVphase((kt - 1) % 3, (kt - 1) & 1);   // independent of S(kt) -> interleaves
    Sphase(kt % 3, kt & 1);
    asm volatile("s_waitcnt vmcnt(0) lgkmcnt(0)" ::: "memory");  // own DMA + P stores landed
    __builtin_amdgcn_s_barrier();
  }
  PVphase(127 % 3, 127 & 1);  // final tile; P/V resident (last barrier covered them)

  // denominator: lane holds sum over keys {ks*16+lh*4..+3} for row rg*16+l15;
  // reduce across lh groups (lanes +16, +32)
  lacc += __shfl_xor(lacc, 16);
  lacc += __shfl_xor(lacc, 32);
  if (lh == 0) lsh[ks][rg * 16 + l15] = lacc;
  __syncthreads();

#pragma unroll
  for (int rf = 0; rf < 4; ++rf)
#pragma unroll
    for (int cf = 0; cf < 4; ++cf) {
      int colL = wo * 64 + cf * 16 + l15;
      for (int j = 0; j < 4; ++j) {
        int sl = rf * 16 + lh * 4 + j;
        if (sl < rem) {
          float linv = 1.f / (lsh[0][sl] + lsh[1][sl]);
          int rl = rsh[sl];
          out[(size_t)(keybase + rl) * 512 + colL] = acc[rf][cf][j] * linv;
        }
      }
    }
}

extern "C" void kernel_launch(void* const* d_in, const int* in_sizes, int n_in,
                              void* d_out, int out_size, void* d_ws, size_t ws_size,
                              hipStream_t stream) {
  const float* x    = (const float*)d_in[0];
  const float* mask = (const float*)d_in[1];
  const float* w1   = (const float*)d_in[2];
  const float* b1   = (const float*)d_in[3];
  const float* w2   = (const float*)d_in[4];
  const float* b2   = (const float*)d_in[5];
  const float* wgt  = (const float*)d_in[6];
  float* out = (float*)d_out;

  char* ws = (char*)d_ws;
  unsigned short* Xb   = (unsigned short*)(ws);               // 33,554,432 B
  unsigned short* QK   = (unsigned short*)(ws + 33554432);    //  8,388,608 B
  unsigned short* SupT = (unsigned short*)(ws + 41943040);    // 33,554,432 B
  unsigned short* Wt   = (unsigned short*)(ws + 75497472);    //    655,360 B
  float* bias          = (float*)(ws + 76152832);             //      2,560 B
  int*   cnt           = (int*)(ws + 76417536);               //         32 B
  int*   ridx          = (int*)(ws + 76417664);               //    131,072 B

  build_w<<<dim3(1280), dim3(256), 0, stream>>>(w1, w2, wgt, b1, b2, Wt, bias);
  compact_rows<<<dim3(8), dim3(256), 0, stream>>>(mask, cnt, ridx);
  cast_x<<<dim3(8192), dim3(256), 0, stream>>>(x, Xb);
  proj_gemm<<<dim3(5, 256), dim3(256), 0, stream>>>(Xb, Wt, bias, QK, SupT);
  attn_kernel<<<dim3(512), dim3(512), 0, stream>>>(QK, SupT, cnt, ridx, out);
  zero_masked<<<dim3(16384), dim3(256), 0, stream>>>(mask, out);
}